// Round 7
// baseline (464.232 us; speedup 1.0000x reference)
//
#include <hip/hip_runtime.h>

// Problem constants
#define B_   256
#define T_   500
#define DIN  700
#define KP   704      // padded K (fragment-packed W)
#define H_   200
#define NO   400      // H*BR
#define DOUT 35
#define NKC  22       // K chunks of 32

typedef _Float16 half_t;
typedef __attribute__((ext_vector_type(8))) _Float16 half8;
typedef __attribute__((ext_vector_type(4))) float floatx4;

#define SX 16.0f      // exact pow2 scale for x
#define SW 4096.0f    // exact pow2 scale for W
#define INV_S (1.0f / 65536.0f)

__device__ __forceinline__ float sigmoidf_(float x) {
    return 1.0f / (1.0f + expf(-x));
}

// ---------------------------------------------------------------------------
// Pre-pass: W -> (hi,lo) fp16 in MFMA-fragment order.
// t = ((kc*25 + nfg)*64 + lane); lane = la + 16*lb.
// value j = W[nfg*16+la][kc*32 + lb*8 + j] (0 beyond col 700), scaled by SW.
__global__ __launch_bounds__(256) void cvt_wfrag(
    const float* __restrict__ W, half_t* __restrict__ Whf, half_t* __restrict__ Wlf)
{
    int t = blockIdx.x * 256 + threadIdx.x;
    if (t >= NKC * 25 * 64) return;
    int lane = t & 63;
    int rest = t >> 6;
    int nfg  = rest % 25;
    int kc   = rest / 25;
    int la = lane & 15, lb = lane >> 4;
    int row = nfg * 16 + la;
    int col = kc * 32 + lb * 8;
    half8 hh, ll;
    #pragma unroll
    for (int j = 0; j < 8; ++j) {
        float v = (col + j < DIN) ? W[(size_t)row * DIN + col + j] : 0.0f;
        float s = v * SW;
        half_t h = (half_t)s;
        hh[j] = h;
        ll[j] = (half_t)(s - (float)h);
    }
    *reinterpret_cast<half8*>(&Whf[(size_t)t * 8]) = hh;
    *reinterpret_cast<half8*>(&Wlf[(size_t)t * 8]) = ll;
}

// ---------------------------------------------------------------------------
// LDS-free split-fp16 MFMA GEMM, 32x80 wave tile, 3 waves/SIMD, counted-wait
// pipeline: A (HBM) prefetched 2 chunks ahead, B (L2) 1 chunk ahead; source
// order engineered so compiler emits counted vmcnt (never drains the A queue).
__global__ __launch_bounds__(256, 3) void dh_gemm_p2(
    const float* __restrict__ x,
    const half_t* __restrict__ Whf, const half_t* __restrict__ Wlf,
    const float* __restrict__ bin, float* __restrict__ Y)
{
    // XCD-bijective swizzle: nwg=5000 = 8*625 exactly; 5 consecutive L share
    // the same 128-row A panel on one XCD.
    int p = blockIdx.x;
    int L = (p & 7) * 625 + (p >> 3);
    int by = L / 5, bx = L - by * 5;

    const int w    = threadIdx.x >> 6;
    const int lane = threadIdx.x & 63;
    const int la   = lane & 15;
    const int lb   = lane >> 4;

    const int m0 = by * 128 + w * 32;    // this wave's 32 M rows
    const int o0 = bx * 80;

    floatx4 acc[2][5];
    #pragma unroll
    for (int mf = 0; mf < 2; ++mf)
        #pragma unroll
        for (int nf = 0; nf < 5; ++nf) {
            floatx4 z = {0.f, 0.f, 0.f, 0.f};
            acc[mf][nf] = z;
        }

    size_t arow[2];
    #pragma unroll
    for (int mf = 0; mf < 2; ++mf)
        arow[mf] = (size_t)(m0 + mf * 16 + la) * DIN;
    const size_t bbase = ((size_t)(bx * 5) * 64 + lane) * 8;

    float4 raA[2][2], raB[2][2];   // A chunk buffers (even/odd), named (rule 20)
    half8 bh[5], bl[5];            // B single buffer, 1-chunk-ahead
    half8 ah[2], al[2];

    auto LOADA = [&](float4 (&ra)[2][2], int kc) {
        const int col = kc * 32 + lb * 8;
        const int c2ofs = (col + 8 <= DIN) ? 4 : (692 - col);  // clamp tail
        #pragma unroll
        for (int mf = 0; mf < 2; ++mf) {
            const float* ptr = &x[arow[mf] + col];
            ra[mf][0] = *reinterpret_cast<const float4*>(ptr);
            ra[mf][1] = *reinterpret_cast<const float4*>(ptr + c2ofs);
        }
    };
    auto LOADB = [&](int kc) {
        const size_t kofs = (size_t)kc * 25 * 64 * 8;
        #pragma unroll
        for (int nf = 0; nf < 5; ++nf) {
            size_t idx = bbase + kofs + (size_t)nf * 64 * 8;
            bh[nf] = *reinterpret_cast<const half8*>(&Whf[idx]);
            bl[nf] = *reinterpret_cast<const half8*>(&Wlf[idx]);
        }
    };
    auto CONV = [&](const float4 (&ra)[2][2]) {
        #pragma unroll
        for (int mf = 0; mf < 2; ++mf) {
            float vv[8];
            *reinterpret_cast<float4*>(&vv[0]) = ra[mf][0];
            *reinterpret_cast<float4*>(&vv[4]) = ra[mf][1];
            half8 hh, ll;
            #pragma unroll
            for (int j = 0; j < 8; ++j) {
                float s = vv[j] * SX;
                half_t h = (half_t)s;
                hh[j] = h;
                ll[j] = (half_t)(s - (float)h);
            }
            ah[mf] = hh;
            al[mf] = ll;
        }
    };
    auto MFMAS = [&]() {
        #pragma unroll
        for (int mf = 0; mf < 2; ++mf)
            #pragma unroll
            for (int nf = 0; nf < 5; ++nf)
                acc[mf][nf] = __builtin_amdgcn_mfma_f32_16x16x32_f16(ah[mf], bh[nf], acc[mf][nf], 0, 0, 0);
        #pragma unroll
        for (int mf = 0; mf < 2; ++mf)
            #pragma unroll
            for (int nf = 0; nf < 5; ++nf)
                acc[mf][nf] = __builtin_amdgcn_mfma_f32_16x16x32_f16(ah[mf], bl[nf], acc[mf][nf], 0, 0, 0);
        #pragma unroll
        for (int mf = 0; mf < 2; ++mf)
            #pragma unroll
            for (int nf = 0; nf < 5; ++nf)
                acc[mf][nf] = __builtin_amdgcn_mfma_f32_16x16x32_f16(al[mf], bh[nf], acc[mf][nf], 0, 0, 0);
    };

    // prologue: chunk 0 and 1 A-loads, chunk 0 B-load
    LOADA(raA, 0);
    LOADB(0);
    LOADA(raB, 1);

    #pragma unroll 1
    for (int I = 0; I < NKC / 2; ++I) {
        const int kc = 2 * I;
        // ---- chunk kc (A in raA, B(kc) in bh/bl) ----
        CONV(raA);                         // waits A(kc); 24 newer stay in flight
        if (kc + 2 < NKC) LOADA(raA, kc + 2);   // A 2-ahead into freed buffer
        MFMAS();                           // uses B(kc)
        LOADB(kc + 1);                     // B 1-ahead (kc+1 <= 21 always)
        // ---- chunk kc+1 (A in raB, B(kc+1) in bh/bl) ----
        CONV(raB);
        if (kc + 3 < NKC) LOADA(raB, kc + 3);
        MFMAS();                           // uses B(kc+1)
        if (kc + 2 < NKC) LOADB(kc + 2);
    }

    // epilogue: C/D layout col = lane&15, row = (lane>>4)*4 + reg
    float bo[5];
    #pragma unroll
    for (int nf = 0; nf < 5; ++nf) bo[nf] = bin[o0 + nf * 16 + la];

    #pragma unroll
    for (int mf = 0; mf < 2; ++mf) {
        int mbase = m0 + mf * 16 + lb * 4;
        #pragma unroll
        for (int rg = 0; rg < 4; ++rg) {
            int mm = mbase + rg;
            int bb = mm / T_;
            int tt = mm - bb * T_;
            float* yrow = &Y[((size_t)tt * B_ + bb) * NO + o0 + la];
            #pragma unroll
            for (int nf = 0; nf < 5; ++nf)
                yrow[nf * 16] = acc[mf][nf][rg] * INV_S + bo[nf];
        }
    }
}

// ---------------------------------------------------------------------------
// Fallback fp32 GEMM (known-good) if workspace too small.
#define BM 256
#define BN 64
#define BK 16
__global__ __launch_bounds__(256) void dh_gemm_in(
    const float* __restrict__ x, const float* __restrict__ Wt,
    const float* __restrict__ bin, float* __restrict__ Y)
{
    __shared__ float As[BK][BM + 4];
    __shared__ float Bs[BK][BN + 4];
    const int tid = threadIdx.x;
    const int tx = tid & 7;
    const int ty = tid >> 3;
    const int m0 = blockIdx.y * BM;
    const int o0 = blockIdx.x * BN;

    float acc[8][8];
    #pragma unroll
    for (int r = 0; r < 8; ++r)
        #pragma unroll
        for (int c = 0; c < 8; ++c) acc[r][c] = 0.0f;

    const int srow = tid >> 2;
    const int skq  = (tid & 3) << 2;

    for (int k0 = 0; k0 < DIN; k0 += BK) {
        float4 areg[4];
        #pragma unroll
        for (int i = 0; i < 4; ++i) {
            int idx = tid + i * 256;
            int row = idx >> 2;
            int kq  = (idx & 3) << 2;
            int kg  = k0 + kq;
            if (kg < DIN)
                areg[i] = *reinterpret_cast<const float4*>(&x[(size_t)(m0 + row) * DIN + kg]);
            else
                areg[i] = make_float4(0.f, 0.f, 0.f, 0.f);
        }
        float4 breg;
        {
            int kg = k0 + skq;
            int o  = o0 + srow;
            if (kg < DIN && o < NO)
                breg = *reinterpret_cast<const float4*>(&Wt[(size_t)o * DIN + kg]);
            else
                breg = make_float4(0.f, 0.f, 0.f, 0.f);
        }
        __syncthreads();
        #pragma unroll
        for (int i = 0; i < 4; ++i) {
            int idx = tid + i * 256;
            int row = idx >> 2;
            int kq  = (idx & 3) << 2;
            As[kq + 0][row] = areg[i].x;
            As[kq + 1][row] = areg[i].y;
            As[kq + 2][row] = areg[i].z;
            As[kq + 3][row] = areg[i].w;
        }
        Bs[skq + 0][srow] = breg.x;
        Bs[skq + 1][srow] = breg.y;
        Bs[skq + 2][srow] = breg.z;
        Bs[skq + 3][srow] = breg.w;
        __syncthreads();

        #pragma unroll
        for (int k = 0; k < BK; ++k) {
            float a[8], bb[8];
            *reinterpret_cast<float4*>(&a[0])  = *reinterpret_cast<const float4*>(&As[k][ty * 8]);
            *reinterpret_cast<float4*>(&a[4])  = *reinterpret_cast<const float4*>(&As[k][ty * 8 + 4]);
            *reinterpret_cast<float4*>(&bb[0]) = *reinterpret_cast<const float4*>(&Bs[k][tx * 8]);
            *reinterpret_cast<float4*>(&bb[4]) = *reinterpret_cast<const float4*>(&Bs[k][tx * 8 + 4]);
            #pragma unroll
            for (int r = 0; r < 8; ++r)
                #pragma unroll
                for (int c = 0; c < 8; ++c)
                    acc[r][c] = fmaf(a[r], bb[c], acc[r][c]);
        }
    }

    float bo[8];
    #pragma unroll
    for (int c = 0; c < 8; ++c) {
        int o = o0 + tx * 8 + c;
        bo[c] = (o < NO) ? bin[o] : 0.0f;
    }
    const int ob = o0 + tx * 8;
    if (ob < NO) {
        #pragma unroll
        for (int r = 0; r < 8; ++r) {
            int m = m0 + ty * 8 + r;
            int b = m / T_;
            int t = m - b * T_;
            float* yrow = &Y[((size_t)t * B_ + b) * NO];
            float4 v0 = make_float4(acc[r][0] + bo[0], acc[r][1] + bo[1],
                                    acc[r][2] + bo[2], acc[r][3] + bo[3]);
            float4 v1 = make_float4(acc[r][4] + bo[4], acc[r][5] + bo[5],
                                    acc[r][6] + bo[6], acc[r][7] + bo[7]);
            *reinterpret_cast<float4*>(&yrow[ob])     = v0;
            *reinterpret_cast<float4*>(&yrow[ob + 4]) = v1;
        }
    }
}

// ---------------------------------------------------------------------------
// Phase 2: sequential LIF scan over T per (b,h) neuron.
__global__ __launch_bounds__(64) void dh_scan(
    const float* __restrict__ Y, const float* __restrict__ tau_n,
    const float* __restrict__ tau_m, float* __restrict__ counts)
{
    int g = blockIdx.x * 64 + threadIdx.x;   // b*H + h
    int b = g / H_;
    int h = g - b * H_;
    (void)b;
    float beta0 = sigmoidf_(tau_n[h * 2 + 0]);
    float beta1 = sigmoidf_(tau_n[h * 2 + 1]);
    float alpha = sigmoidf_(tau_m[h]);
    float omb0 = 1.0f - beta0, omb1 = 1.0f - beta1, oma = 1.0f - alpha;
    const float2* Yp = reinterpret_cast<const float2*>(Y);

    float v = 0.f, i0 = 0.f, i1 = 0.f, cnt = 0.f;
    #pragma unroll 1
    for (int t0 = 0; t0 < T_; t0 += 10) {
        float2 yb[10];
        #pragma unroll
        for (int j = 0; j < 10; ++j)
            yb[j] = Yp[(size_t)(t0 + j) * (B_ * H_) + g];
        #pragma unroll
        for (int j = 0; j < 10; ++j) {
            i0 = beta0 * i0 + omb0 * yb[j].x;
            i1 = beta1 * i1 + omb1 * yb[j].y;
            float it = i0 + i1;
            v = alpha * v + oma * it;
            if (v >= 1.0f) { v -= 1.0f; cnt += 1.0f; }
        }
    }
    counts[g] = cnt;
}

// Phase 3: out[b][o] = sum_h counts[b][h] * W_out[o][h] + b_out[o]
__global__ __launch_bounds__(64) void dh_out(
    const float* __restrict__ counts, const float* __restrict__ W_out,
    const float* __restrict__ b_out, float* __restrict__ out)
{
    int b = blockIdx.x;
    int o = threadIdx.x;
    if (o >= DOUT) return;
    float acc = b_out[o];
    const float* c = &counts[(size_t)b * H_];
    const float* w = &W_out[(size_t)o * H_];
    #pragma unroll 4
    for (int h = 0; h < H_; ++h)
        acc = fmaf(c[h], w[h], acc);
    out[(size_t)b * DOUT + o] = acc;
}

extern "C" void kernel_launch(void* const* d_in, const int* in_sizes, int n_in,
                              void* d_out, int out_size, void* d_ws, size_t ws_size,
                              hipStream_t stream) {
    const float* x     = (const float*)d_in[0];  // (B,T,DIN)
    const float* W_in  = (const float*)d_in[1];  // (NO,DIN)
    const float* b_in  = (const float*)d_in[2];  // (NO)
    const float* tau_n = (const float*)d_in[3];  // (H,BR)
    const float* tau_m = (const float*)d_in[4];  // (H)
    const float* W_out = (const float*)d_in[5];  // (DOUT,H)
    const float* b_out = (const float*)d_in[6];  // (DOUT)
    float* out = (float*)d_out;                  // (B,DOUT)

    float* Y      = (float*)d_ws;                         // 51.2M floats
    float* counts = Y + (size_t)T_ * B_ * NO;             // 51200 floats

    const size_t nfrag_halves = (size_t)NKC * 25 * 64 * 8;   // 281600
    size_t need = ((size_t)T_ * B_ * NO + (size_t)B_ * H_) * 4
                + 2 * nfrag_halves * 2;

    if (ws_size >= need) {
        half_t* Whf = (half_t*)(counts + (size_t)B_ * H_);
        half_t* Wlf = Whf + nfrag_halves;

        cvt_wfrag<<<(NKC * 25 * 64 + 255) / 256, 256, 0, stream>>>(W_in, Whf, Wlf);
        dh_gemm_p2<<<5000, 256, 0, stream>>>(x, Whf, Wlf, b_in, Y);
    } else {
        dim3 g1(7, 500);
        dh_gemm_in<<<g1, 500 == 500 ? 256 : 256, 0, stream>>>(x, W_in, b_in, Y);
    }

    dh_scan<<<(B_ * H_) / 64, 64, 0, stream>>>(Y, tau_n, tau_m, counts);
    dh_out<<<B_, 64, 0, stream>>>(counts, W_out, b_out, out);
}

// Round 8
// 371.263 us; speedup vs baseline: 1.2504x; 1.2504x over previous
//
#include <hip/hip_runtime.h>

// Problem constants
#define B_   256
#define T_   500
#define DIN  700
#define KP   704      // padded K (fragment-packed W)
#define H_   200
#define NO   400      // H*BR
#define DOUT 35
#define NKC  22       // K chunks of 32

typedef _Float16 half_t;
typedef __attribute__((ext_vector_type(8))) _Float16 half8;
typedef __attribute__((ext_vector_type(4))) float floatx4;

#define SX 16.0f      // exact pow2 scale for x
#define SW 4096.0f    // exact pow2 scale for W
#define INV_S (1.0f / 65536.0f)

__device__ __forceinline__ float sigmoidf_(float x) {
    return 1.0f / (1.0f + expf(-x));
}

// ---------------------------------------------------------------------------
// Pre-pass: W -> (hi,lo) fp16 in MFMA-fragment order.
// t = ((kc*25 + nfg)*64 + lane); lane = la + 16*lb.
// value j = W[nfg*16+la][kc*32 + lb*8 + j] (0 beyond col 700), scaled by SW.
__global__ __launch_bounds__(256) void cvt_wfrag(
    const float* __restrict__ W, half_t* __restrict__ Whf, half_t* __restrict__ Wlf)
{
    int t = blockIdx.x * 256 + threadIdx.x;
    if (t >= NKC * 25 * 64) return;
    int lane = t & 63;
    int rest = t >> 6;
    int nfg  = rest % 25;
    int kc   = rest / 25;
    int la = lane & 15, lb = lane >> 4;
    int row = nfg * 16 + la;
    int col = kc * 32 + lb * 8;
    half8 hh, ll;
    #pragma unroll
    for (int j = 0; j < 8; ++j) {
        float v = (col + j < DIN) ? W[(size_t)row * DIN + col + j] : 0.0f;
        float s = v * SW;
        half_t h = (half_t)s;
        hh[j] = h;
        ll[j] = (half_t)(s - (float)h);
    }
    *reinterpret_cast<half8*>(&Whf[(size_t)t * 8]) = hh;
    *reinterpret_cast<half8*>(&Wlf[(size_t)t * 8]) = ll;
}

// ---------------------------------------------------------------------------
// LDS-free split-fp16 MFMA GEMM, 64x80 wave tile, __launch_bounds__(256,1):
// 512 VGPRs/wave so the compiler KEEPS the full double-buffered pipeline in
// registers instead of serializing (rounds 4-7 post-mortem: VGPR_Count 84-128
// proved the dbuf was dropped). Retirement-order-correct counted pipeline:
// per iter [CONV(A kc); LOADA(kc+2); MFMAS(B kc); LOADB(kc+2)] — waiting for
// B(kc) retires only loads issued before it; A(kc+1..2), B(kc+1) stay in
// flight. sched_barrier(0) fences pin the stream order.
__global__ __launch_bounds__(256, 1) void dh_gemm_deep(
    const float* __restrict__ x,
    const half_t* __restrict__ Whf, const half_t* __restrict__ Wlf,
    const float* __restrict__ bin, float* __restrict__ Y)
{
    // XCD-bijective swizzle: nwg=2500, 8 XCDs (q=312, r=4)
    int p = blockIdx.x;
    int xcd = p & 7, slot = p >> 3;
    int L = (xcd < 4 ? xcd * 313 : 4 * 313 + (xcd - 4) * 312) + slot;

    const int w    = threadIdx.x >> 6;
    const int lane = threadIdx.x & 63;
    const int la   = lane & 15;
    const int lb   = lane >> 4;

    const int wave = L * 4 + w;          // 0..9999
    const int mt = wave / 5, nt = wave - mt * 5;
    const int m0 = mt * 64;              // 64 M rows (shared by 4-of-5 waves in block -> L1 A reuse)
    const int o0 = nt * 80;              // 80 N cols

    floatx4 acc[4][5];
    #pragma unroll
    for (int mf = 0; mf < 4; ++mf)
        #pragma unroll
        for (int nf = 0; nf < 5; ++nf) {
            floatx4 z = {0.f, 0.f, 0.f, 0.f};
            acc[mf][nf] = z;
        }

    size_t arow[4];
    #pragma unroll
    for (int mf = 0; mf < 4; ++mf)
        arow[mf] = (size_t)(m0 + mf * 16 + la) * DIN;
    const size_t bbase = ((size_t)(nt * 5) * 64 + lane) * 8;

    float4 aE[4][2], aO[4][2];           // named A buffers (rule 20)
    half8 bEh[5], bEl[5], bOh[5], bOl[5];
    half8 ah[4], al[4];

    auto LOADA = [&](float4 (&ra)[4][2], int kc) {
        const int col = kc * 32 + lb * 8;
        const int c2ofs = (col + 8 <= DIN) ? 4 : (692 - col);  // clamp tail into valid x
        #pragma unroll
        for (int mf = 0; mf < 4; ++mf) {
            const float* ptr = &x[arow[mf] + col];
            ra[mf][0] = *reinterpret_cast<const float4*>(ptr);
            ra[mf][1] = *reinterpret_cast<const float4*>(ptr + c2ofs);
        }
    };
    auto LOADB = [&](half8 (&bh)[5], half8 (&bl)[5], int kc) {
        const size_t kofs = (size_t)kc * 25 * 64 * 8;
        #pragma unroll
        for (int nf = 0; nf < 5; ++nf) {
            size_t idx = bbase + kofs + (size_t)nf * 64 * 8;
            bh[nf] = *reinterpret_cast<const half8*>(&Whf[idx]);
            bl[nf] = *reinterpret_cast<const half8*>(&Wlf[idx]);
        }
    };
    auto CONV = [&](const float4 (&ra)[4][2]) {
        #pragma unroll
        for (int mf = 0; mf < 4; ++mf) {
            float vv[8];
            *reinterpret_cast<float4*>(&vv[0]) = ra[mf][0];
            *reinterpret_cast<float4*>(&vv[4]) = ra[mf][1];
            half8 hh, ll;
            #pragma unroll
            for (int j = 0; j < 8; ++j) {
                float s = vv[j] * SX;
                half_t h = (half_t)s;
                hh[j] = h;
                ll[j] = (half_t)(s - (float)h);
            }
            ah[mf] = hh;
            al[mf] = ll;
        }
    };
    auto MFMAS = [&](const half8 (&bh)[5], const half8 (&bl)[5]) {
        #pragma unroll
        for (int mf = 0; mf < 4; ++mf)
            #pragma unroll
            for (int nf = 0; nf < 5; ++nf)
                acc[mf][nf] = __builtin_amdgcn_mfma_f32_16x16x32_f16(ah[mf], bh[nf], acc[mf][nf], 0, 0, 0);
        #pragma unroll
        for (int mf = 0; mf < 4; ++mf)
            #pragma unroll
            for (int nf = 0; nf < 5; ++nf)
                acc[mf][nf] = __builtin_amdgcn_mfma_f32_16x16x32_f16(ah[mf], bl[nf], acc[mf][nf], 0, 0, 0);
        #pragma unroll
        for (int mf = 0; mf < 4; ++mf)
            #pragma unroll
            for (int nf = 0; nf < 5; ++nf)
                acc[mf][nf] = __builtin_amdgcn_mfma_f32_16x16x32_f16(al[mf], bh[nf], acc[mf][nf], 0, 0, 0);
    };

    // prologue: A0 B0 A1 B1 (A first so its HBM fetch starts earliest)
    LOADA(aE, 0);
    LOADB(bEh, bEl, 0);
    LOADA(aO, 1);
    LOADB(bOh, bOl, 1);

    #pragma unroll 1
    for (int I = 0; I < 10; ++I) {
        const int kc = 2 * I;
        // ---- even chunk kc ----
        __builtin_amdgcn_sched_barrier(0);
        CONV(aE);                         // waits A(kc), ~2 walls old
        __builtin_amdgcn_sched_barrier(0);
        LOADA(aE, kc + 2);                // A 2-ahead into freed buffer
        __builtin_amdgcn_sched_barrier(0);
        MFMAS(bEh, bEl);                  // waits B(kc); A(kc+1),B(kc+1),A(kc+2) stay in flight
        __builtin_amdgcn_sched_barrier(0);
        LOADB(bEh, bEl, kc + 2);
        // ---- odd chunk kc+1 ----
        __builtin_amdgcn_sched_barrier(0);
        CONV(aO);                         // waits A(kc+1)
        __builtin_amdgcn_sched_barrier(0);
        LOADA(aO, kc + 3);
        __builtin_amdgcn_sched_barrier(0);
        MFMAS(bOh, bOl);                  // waits B(kc+1)
        __builtin_amdgcn_sched_barrier(0);
        LOADB(bOh, bOl, kc + 3);
    }
    // tail: chunks 20, 21 (already loaded by I=9)
    __builtin_amdgcn_sched_barrier(0);
    CONV(aE);
    MFMAS(bEh, bEl);
    CONV(aO);
    MFMAS(bOh, bOl);

    // epilogue: C/D layout col = lane&15, row = (lane>>4)*4 + reg
    float bo[5];
    #pragma unroll
    for (int nf = 0; nf < 5; ++nf) bo[nf] = bin[o0 + nf * 16 + la];

    #pragma unroll
    for (int mf = 0; mf < 4; ++mf) {
        int mbase = m0 + mf * 16 + lb * 4;
        #pragma unroll
        for (int rg = 0; rg < 4; ++rg) {
            int mm = mbase + rg;
            int bb = mm / T_;
            int tt = mm - bb * T_;
            float* yrow = &Y[((size_t)tt * B_ + bb) * NO + o0 + la];
            #pragma unroll
            for (int nf = 0; nf < 5; ++nf)
                yrow[nf * 16] = acc[mf][nf][rg] * INV_S + bo[nf];
        }
    }
}

// ---------------------------------------------------------------------------
// Fallback fp32 GEMM (known-good) if workspace too small.
#define BM 256
#define BN 64
#define BK 16
__global__ __launch_bounds__(256) void dh_gemm_in(
    const float* __restrict__ x, const float* __restrict__ Wt,
    const float* __restrict__ bin, float* __restrict__ Y)
{
    __shared__ float As[BK][BM + 4];
    __shared__ float Bs[BK][BN + 4];
    const int tid = threadIdx.x;
    const int tx = tid & 7;
    const int ty = tid >> 3;
    const int m0 = blockIdx.y * BM;
    const int o0 = blockIdx.x * BN;

    float acc[8][8];
    #pragma unroll
    for (int r = 0; r < 8; ++r)
        #pragma unroll
        for (int c = 0; c < 8; ++c) acc[r][c] = 0.0f;

    const int srow = tid >> 2;
    const int skq  = (tid & 3) << 2;

    for (int k0 = 0; k0 < DIN; k0 += BK) {
        float4 areg[4];
        #pragma unroll
        for (int i = 0; i < 4; ++i) {
            int idx = tid + i * 256;
            int row = idx >> 2;
            int kq  = (idx & 3) << 2;
            int kg  = k0 + kq;
            if (kg < DIN)
                areg[i] = *reinterpret_cast<const float4*>(&x[(size_t)(m0 + row) * DIN + kg]);
            else
                areg[i] = make_float4(0.f, 0.f, 0.f, 0.f);
        }
        float4 breg;
        {
            int kg = k0 + skq;
            int o  = o0 + srow;
            if (kg < DIN && o < NO)
                breg = *reinterpret_cast<const float4*>(&Wt[(size_t)o * DIN + kg]);
            else
                breg = make_float4(0.f, 0.f, 0.f, 0.f);
        }
        __syncthreads();
        #pragma unroll
        for (int i = 0; i < 4; ++i) {
            int idx = tid + i * 256;
            int row = idx >> 2;
            int kq  = (idx & 3) << 2;
            As[kq + 0][row] = areg[i].x;
            As[kq + 1][row] = areg[i].y;
            As[kq + 2][row] = areg[i].z;
            As[kq + 3][row] = areg[i].w;
        }
        Bs[skq + 0][srow] = breg.x;
        Bs[skq + 1][srow] = breg.y;
        Bs[skq + 2][srow] = breg.z;
        Bs[skq + 3][srow] = breg.w;
        __syncthreads();

        #pragma unroll
        for (int k = 0; k < BK; ++k) {
            float a[8], bb[8];
            *reinterpret_cast<float4*>(&a[0])  = *reinterpret_cast<const float4*>(&As[k][ty * 8]);
            *reinterpret_cast<float4*>(&a[4])  = *reinterpret_cast<const float4*>(&As[k][ty * 8 + 4]);
            *reinterpret_cast<float4*>(&bb[0]) = *reinterpret_cast<const float4*>(&Bs[k][tx * 8]);
            *reinterpret_cast<float4*>(&bb[4]) = *reinterpret_cast<const float4*>(&Bs[k][tx * 8 + 4]);
            #pragma unroll
            for (int r = 0; r < 8; ++r)
                #pragma unroll
                for (int c = 0; c < 8; ++c)
                    acc[r][c] = fmaf(a[r], bb[c], acc[r][c]);
        }
    }

    float bo[8];
    #pragma unroll
    for (int c = 0; c < 8; ++c) {
        int o = o0 + tx * 8 + c;
        bo[c] = (o < NO) ? bin[o] : 0.0f;
    }
    const int ob = o0 + tx * 8;
    if (ob < NO) {
        #pragma unroll
        for (int r = 0; r < 8; ++r) {
            int m = m0 + ty * 8 + r;
            int b = m / T_;
            int t = m - b * T_;
            float* yrow = &Y[((size_t)t * B_ + b) * NO];
            float4 v0 = make_float4(acc[r][0] + bo[0], acc[r][1] + bo[1],
                                    acc[r][2] + bo[2], acc[r][3] + bo[3]);
            float4 v1 = make_float4(acc[r][4] + bo[4], acc[r][5] + bo[5],
                                    acc[r][6] + bo[6], acc[r][7] + bo[7]);
            *reinterpret_cast<float4*>(&yrow[ob])     = v0;
            *reinterpret_cast<float4*>(&yrow[ob + 4]) = v1;
        }
    }
}

// ---------------------------------------------------------------------------
// Phase 2: sequential LIF scan over T per (b,h) neuron.
__global__ __launch_bounds__(64) void dh_scan(
    const float* __restrict__ Y, const float* __restrict__ tau_n,
    const float* __restrict__ tau_m, float* __restrict__ counts)
{
    int g = blockIdx.x * 64 + threadIdx.x;   // b*H + h
    int b = g / H_;
    int h = g - b * H_;
    (void)b;
    float beta0 = sigmoidf_(tau_n[h * 2 + 0]);
    float beta1 = sigmoidf_(tau_n[h * 2 + 1]);
    float alpha = sigmoidf_(tau_m[h]);
    float omb0 = 1.0f - beta0, omb1 = 1.0f - beta1, oma = 1.0f - alpha;
    const float2* Yp = reinterpret_cast<const float2*>(Y);

    float v = 0.f, i0 = 0.f, i1 = 0.f, cnt = 0.f;
    #pragma unroll 1
    for (int t0 = 0; t0 < T_; t0 += 10) {
        float2 yb[10];
        #pragma unroll
        for (int j = 0; j < 10; ++j)
            yb[j] = Yp[(size_t)(t0 + j) * (B_ * H_) + g];
        #pragma unroll
        for (int j = 0; j < 10; ++j) {
            i0 = beta0 * i0 + omb0 * yb[j].x;
            i1 = beta1 * i1 + omb1 * yb[j].y;
            float it = i0 + i1;
            v = alpha * v + oma * it;
            if (v >= 1.0f) { v -= 1.0f; cnt += 1.0f; }
        }
    }
    counts[g] = cnt;
}

// Phase 3: out[b][o] = sum_h counts[b][h] * W_out[o][h] + b_out[o]
__global__ __launch_bounds__(64) void dh_out(
    const float* __restrict__ counts, const float* __restrict__ W_out,
    const float* __restrict__ b_out, float* __restrict__ out)
{
    int b = blockIdx.x;
    int o = threadIdx.x;
    if (o >= DOUT) return;
    float acc = b_out[o];
    const float* c = &counts[(size_t)b * H_];
    const float* w = &W_out[(size_t)o * H_];
    #pragma unroll 4
    for (int h = 0; h < H_; ++h)
        acc = fmaf(c[h], w[h], acc);
    out[(size_t)b * DOUT + o] = acc;
}

extern "C" void kernel_launch(void* const* d_in, const int* in_sizes, int n_in,
                              void* d_out, int out_size, void* d_ws, size_t ws_size,
                              hipStream_t stream) {
    const float* x     = (const float*)d_in[0];  // (B,T,DIN)
    const float* W_in  = (const float*)d_in[1];  // (NO,DIN)
    const float* b_in  = (const float*)d_in[2];  // (NO)
    const float* tau_n = (const float*)d_in[3];  // (H,BR)
    const float* tau_m = (const float*)d_in[4];  // (H)
    const float* W_out = (const float*)d_in[5];  // (DOUT,H)
    const float* b_out = (const float*)d_in[6];  // (DOUT)
    float* out = (float*)d_out;                  // (B,DOUT)

    float* Y      = (float*)d_ws;                         // 51.2M floats
    float* counts = Y + (size_t)T_ * B_ * NO;             // 51200 floats

    const size_t nfrag_halves = (size_t)NKC * 25 * 64 * 8;   // 281600
    size_t need = ((size_t)T_ * B_ * NO + (size_t)B_ * H_) * 4
                + 2 * nfrag_halves * 2;

    if (ws_size >= need) {
        half_t* Whf = (half_t*)(counts + (size_t)B_ * H_);
        half_t* Wlf = Whf + nfrag_halves;

        cvt_wfrag<<<(NKC * 25 * 64 + 255) / 256, 256, 0, stream>>>(W_in, Whf, Wlf);
        dh_gemm_deep<<<2500, 256, 0, stream>>>(x, Whf, Wlf, b_in, Y);
    } else {
        dim3 g1(7, 500);
        dh_gemm_in<<<g1, 256, 0, stream>>>(x, W_in, b_in, Y);
    }

    dh_scan<<<(B_ * H_) / 64, 64, 0, stream>>>(Y, tau_n, tau_m, counts);
    dh_out<<<B_, 64, 0, stream>>>(counts, W_out, b_out, out);
}